// Round 1
// baseline (26277.682 us; speedup 1.0000x reference)
//
#include <hip/hip_runtime.h>
#include <hip/hip_bf16.h>

#define SEQ   200
#define BATCH 128
#define NHID  1024
#define NDEPTH 5

typedef __bf16 bf16x8 __attribute__((ext_vector_type(8)));
typedef float  f32x4  __attribute__((ext_vector_type(4)));
typedef __hip_bfloat16 bf16_t;

__device__ __forceinline__ f32x4 mfma16(bf16x8 a, bf16x8 b, f32x4 c) {
    return __builtin_amdgcn_mfma_f32_16x16x32_bf16(a, b, c, 0, 0, 0);
}

__global__ void k_cast_bf16(const float* __restrict__ src, bf16_t* __restrict__ dst, int n) {
    for (int i = blockIdx.x * blockDim.x + threadIdx.x; i < n; i += gridDim.x * blockDim.x)
        dst[i] = __float2bfloat16(src[i]);
}

__global__ void k_prep_xm(const float* __restrict__ inp, const float* __restrict__ h_mask,
                          bf16_t* __restrict__ xm, int n) {
    for (int i = blockIdx.x * blockDim.x + threadIdx.x; i < n; i += gridDim.x * blockDim.x) {
        int r = i & (BATCH * NHID - 1);
        xm[i] = __float2bfloat16(inp[i] * h_mask[r]);
    }
}

__global__ void k_init_state(const float* __restrict__ hidden, const float* __restrict__ s_mask,
                             float* __restrict__ s, bf16_t* __restrict__ smb, int n) {
    for (int i = blockIdx.x * blockDim.x + threadIdx.x; i < n; i += gridDim.x * blockDim.x) {
        float h = hidden[i];
        s[i] = h;
        smb[i] = __float2bfloat16(h * s_mask[i]);
    }
}

// One (step, layer) round. Grid: x = col-tiles (1024/64), y = row-tiles (128/32).
// Block: 256 threads = 4 waves in a 2x2 arrangement; each wave computes a 16x32
// output tile for BOTH gates (H and T) via 2+2 MFMA accumulators.
template<bool L0>
__global__ __launch_bounds__(256) void k_rhn_layer(
    const bf16_t* __restrict__ smb, const bf16_t* __restrict__ xmt,
    const bf16_t* __restrict__ Whl, const bf16_t* __restrict__ Wtl,
    const bf16_t* __restrict__ Wih, const bf16_t* __restrict__ Wit,
    const float* __restrict__ bhl, const float* __restrict__ btl,
    const float* __restrict__ bih, const float* __restrict__ bitv,
    const float* __restrict__ s_mask, float* __restrict__ s,
    bf16_t* __restrict__ smb_out, float* __restrict__ outs, float* __restrict__ lastp)
{
    const int lane = threadIdx.x & 63;
    const int w    = threadIdx.x >> 6;
    const int r0   = blockIdx.y * 32 + (w >> 1) * 16;   // batch-row base of wave tile
    const int c0   = blockIdx.x * 64 + (w & 1) * 32;    // out-col base of wave tile
    const int lr   = lane & 15;                         // 16-dim index within frag
    const int kg   = lane >> 4;                         // k-group (8 contiguous k's)

    f32x4 aH0 = {0.f,0.f,0.f,0.f}, aH1 = {0.f,0.f,0.f,0.f};
    f32x4 aT0 = {0.f,0.f,0.f,0.f}, aT1 = {0.f,0.f,0.f,0.f};

    // --- recurrent GEMM: sm @ Wh^T, sm @ Wt^T  (A, B both K-contiguous rows) ---
    {
        const bf16_t* A   = smb + (size_t)(r0 + lr) * NHID + kg * 8;
        const bf16_t* Bh0 = Whl + (size_t)(c0 + lr) * NHID + kg * 8;
        const bf16_t* Bt0 = Wtl + (size_t)(c0 + lr) * NHID + kg * 8;
        #pragma unroll 4
        for (int k = 0; k < NHID; k += 32) {
            bf16x8 a   = *(const bf16x8*)(A + k);
            bf16x8 bh0 = *(const bf16x8*)(Bh0 + k);
            bf16x8 bh1 = *(const bf16x8*)(Bh0 + 16 * NHID + k);
            bf16x8 bt0 = *(const bf16x8*)(Bt0 + k);
            bf16x8 bt1 = *(const bf16x8*)(Bt0 + 16 * NHID + k);
            aH0 = mfma16(a, bh0, aH0);
            aH1 = mfma16(a, bh1, aH1);
            aT0 = mfma16(a, bt0, aT0);
            aT1 = mfma16(a, bt1, aT1);
        }
    }
    // --- layer 0 only: fold input projection as K-extension: x_t @ Wih^T, x_t @ Wit^T ---
    if (L0) {
        const bf16_t* A   = xmt + (size_t)(r0 + lr) * NHID + kg * 8;
        const bf16_t* Bh0 = Wih + (size_t)(c0 + lr) * NHID + kg * 8;
        const bf16_t* Bt0 = Wit + (size_t)(c0 + lr) * NHID + kg * 8;
        #pragma unroll 4
        for (int k = 0; k < NHID; k += 32) {
            bf16x8 a   = *(const bf16x8*)(A + k);
            bf16x8 bh0 = *(const bf16x8*)(Bh0 + k);
            bf16x8 bh1 = *(const bf16x8*)(Bh0 + 16 * NHID + k);
            bf16x8 bt0 = *(const bf16x8*)(Bt0 + k);
            bf16x8 bt1 = *(const bf16x8*)(Bt0 + 16 * NHID + k);
            aH0 = mfma16(a, bh0, aH0);
            aH1 = mfma16(a, bh1, aH1);
            aT0 = mfma16(a, bt0, aT0);
            aT1 = mfma16(a, bt1, aT1);
        }
    }

    // --- epilogue: C/D mapping col = lane&15, row = (lane>>4)*4 + j  [verified m89/m91] ---
    const int n0 = c0 + lr;
    const int mb = r0 + kg * 4;
    float bhv0 = bhl[n0],      btv0 = btl[n0];
    float bhv1 = bhl[n0 + 16], btv1 = btl[n0 + 16];
    if (L0) {
        bhv0 += bih[n0];       btv0 += bitv[n0];
        bhv1 += bih[n0 + 16];  btv1 += bitv[n0 + 16];
    }

    #pragma unroll
    for (int j = 0; j < 4; ++j) {
        const int b = mb + j;
        {
            const int idx = b * NHID + n0;
            float hp = aH0[j] + bhv0, tp = aT0[j] + btv0;
            float Hv = tanhf(hp);
            float Tv = 1.0f / (1.0f + expf(-tp));
            float sv = s[idx];
            float sn = (Hv - sv) * Tv + sv;
            s[idx] = sn;
            smb_out[idx] = __float2bfloat16(sn * s_mask[idx]);
            if (outs)  outs[idx]  = sn;
            if (lastp) lastp[idx] = sn;
        }
        {
            const int idx = b * NHID + n0 + 16;
            float hp = aH1[j] + bhv1, tp = aT1[j] + btv1;
            float Hv = tanhf(hp);
            float Tv = 1.0f / (1.0f + expf(-tp));
            float sv = s[idx];
            float sn = (Hv - sv) * Tv + sv;
            s[idx] = sn;
            smb_out[idx] = __float2bfloat16(sn * s_mask[idx]);
            if (outs)  outs[idx]  = sn;
            if (lastp) lastp[idx] = sn;
        }
    }
}

extern "C" void kernel_launch(void* const* d_in, const int* in_sizes, int n_in,
                              void* d_out, int out_size, void* d_ws, size_t ws_size,
                              hipStream_t stream) {
    (void)in_sizes; (void)n_in; (void)out_size; (void)ws_size;

    const float* inp    = (const float*)d_in[0];
    const float* hidden = (const float*)d_in[1];
    const float* h_mask = (const float*)d_in[2];
    const float* s_mask = (const float*)d_in[3];
    const float* Wih    = (const float*)d_in[4];
    const float* bih    = (const float*)d_in[5];
    const float* Wit    = (const float*)d_in[6];
    const float* bitv   = (const float*)d_in[7];
    const float* Wh     = (const float*)d_in[8];
    const float* bh     = (const float*)d_in[9];
    const float* Wt     = (const float*)d_in[10];
    const float* bt     = (const float*)d_in[11];
    float* out = (float*)d_out;

    // workspace layout (bf16 = 2B): Wih 2MB | Wit 2MB | Wh 10MB | Wt 10MB | xm 52.4MB | smb0/1 | s(f32)
    bf16_t* Wih_b = (bf16_t*)d_ws;
    bf16_t* Wit_b = Wih_b + (size_t)NHID * NHID;
    bf16_t* Wh_b  = Wit_b + (size_t)NHID * NHID;
    bf16_t* Wt_b  = Wh_b  + (size_t)NDEPTH * NHID * NHID;
    bf16_t* xm    = Wt_b  + (size_t)NDEPTH * NHID * NHID;
    bf16_t* smb0  = xm    + (size_t)SEQ * BATCH * NHID;
    bf16_t* smb1  = smb0  + (size_t)BATCH * NHID;
    float*  sbuf  = (float*)(smb1 + (size_t)BATCH * NHID);

    dim3 pb(256);
    k_cast_bf16<<<dim3(512),  pb, 0, stream>>>(Wih, Wih_b, NHID * NHID);
    k_cast_bf16<<<dim3(512),  pb, 0, stream>>>(Wit, Wit_b, NHID * NHID);
    k_cast_bf16<<<dim3(1024), pb, 0, stream>>>(Wh,  Wh_b,  NDEPTH * NHID * NHID);
    k_cast_bf16<<<dim3(1024), pb, 0, stream>>>(Wt,  Wt_b,  NDEPTH * NHID * NHID);
    k_prep_xm<<<dim3(2048),   pb, 0, stream>>>(inp, h_mask, xm, SEQ * BATCH * NHID);
    k_init_state<<<dim3(64),  pb, 0, stream>>>(hidden, s_mask, sbuf, smb0, BATCH * NHID);

    bf16_t* smb[2] = {smb0, smb1};
    int p = 0;
    dim3 grid(NHID / 64, BATCH / 32), block(256);
    for (int t = 0; t < SEQ; ++t) {
        for (int l = 0; l < NDEPTH; ++l) {
            const bf16_t* Whl = Wh_b + (size_t)l * NHID * NHID;
            const bf16_t* Wtl = Wt_b + (size_t)l * NHID * NHID;
            const float*  bhl = bh + l * NHID;
            const float*  btl = bt + l * NHID;
            float* outs  = (l == NDEPTH - 1) ? out + (size_t)t * BATCH * NHID : nullptr;
            float* lastp = (l == NDEPTH - 1 && t == SEQ - 1) ? out + (size_t)SEQ * BATCH * NHID : nullptr;
            if (l == 0)
                k_rhn_layer<true><<<grid, block, 0, stream>>>(
                    smb[p], xm + (size_t)t * BATCH * NHID,
                    Whl, Wtl, Wih_b, Wit_b, bhl, btl, bih, bitv,
                    s_mask, sbuf, smb[p ^ 1], outs, lastp);
            else
                k_rhn_layer<false><<<grid, block, 0, stream>>>(
                    smb[p], nullptr,
                    Whl, Wtl, nullptr, nullptr, bhl, btl, nullptr, nullptr,
                    s_mask, sbuf, smb[p ^ 1], outs, lastp);
            p ^= 1;
        }
    }
}